// Round 4
// baseline (643.637 us; speedup 1.0000x reference)
//
#include <hip/hip_runtime.h>
#include <cstdint>
#include <cstddef>
#include <cmath>

#define SEQ 4096
#define DM  2048

typedef unsigned int u32;
typedef unsigned short u16;
typedef __attribute__((ext_vector_type(8))) short bf16x8;
typedef __attribute__((ext_vector_type(4))) float f32x4;
typedef __attribute__((ext_vector_type(16))) float f32x16;

// ---------------- bf16 helpers (RNE) ----------------
__device__ __forceinline__ u16 f2bf(float f) {
  u32 u = __float_as_uint(f);
  return (u16)((u + 0x7FFFu + ((u >> 16) & 1u)) >> 16);
}
__device__ __forceinline__ float bf2f(u16 h) { return __uint_as_float(((u32)h) << 16); }

// ---------------- threefry dropout (verified round 1, variant 0) ----------------
__device__ __forceinline__ u32 rotl32(u32 x, int r) { return (x << r) | (x >> (32 - r)); }

__device__ __forceinline__ void tf2x32(u32 c0, u32 c1, u32& o0, u32& o1) {
  const u32 k0 = 0u, k1 = 42u, k2 = 0x1BD11BDAu ^ 0u ^ 42u;
  u32 x0 = c0 + k0;
  u32 x1 = c1 + k1;
#define TFR(r) { x0 += x1; x1 = rotl32(x1, (r)); x1 ^= x0; }
  TFR(13) TFR(15) TFR(26) TFR(6)   x0 += k1; x1 += k2 + 1u;
  TFR(17) TFR(29) TFR(16) TFR(24)  x0 += k2; x1 += k0 + 2u;
  TFR(13) TFR(15) TFR(26) TFR(6)   x0 += k0; x1 += k1 + 3u;
  TFR(17) TFR(29) TFR(16) TFR(24)  x0 += k1; x1 += k2 + 4u;
  TFR(13) TFR(15) TFR(26) TFR(6)   x0 += k2; x1 += k0 + 5u;
#undef TFR
  o0 = x0; o1 = x1;
}

__device__ __forceinline__ bool dropout_keep(u32 idx) {
  u32 a, b; tf2x32(0u, idx, a, b);
  return (((a ^ b) & 0x80000000u) == 0u);
}

// ---------------- async global -> LDS, 16 B/lane ----------------
__device__ __forceinline__ void g2l16(const void* g, void* l) {
  __builtin_amdgcn_global_load_lds((const __attribute__((address_space(1))) u32*)g,
                                   (__attribute__((address_space(3))) u32*)l, 16, 0, 0);
}

#define MFMA16(a, b, c) __builtin_amdgcn_mfma_f32_16x16x32_bf16(a, b, c, 0, 0, 0)
#define MFMA32(a, b, c) __builtin_amdgcn_mfma_f32_32x32x16_bf16(a, b, c, 0, 0, 0)

// FT32 layout (for 32x32x16 A/B operands) of [R rows][K k]:
// tile = 32 rows x 16 k; elem (rt, kt, lane, j) at (((rt*(K/16)+kt)*64+lane)*8+j)
// where lane holds row rt*32+(lane&31), k = kt*16+(lane>>5)*8+j.
// In round-4 the HI operands are ALSO staged into LDS in FT32 order via
// per-lane pre-swizzled global addresses -> all ds_reads are lane-linear.

// Plain bf16 GEMM core, 16x16x32, BK=64 (kept for k_pv): C = A * B^T.
__device__ __forceinline__ void gemm_core(
    const u16* __restrict__ Ah, const u16* __restrict__ Bh,
    int lda, int ldb, int rowBlock, int colBlock, int kmax,
    f32x4 (&acc)[4][4], u16* smem)
{
  u16* Als = smem;
  u16* Bls = smem + 8192;
  const int tid  = threadIdx.x;
  const int wid  = tid >> 6;
  const int lane = tid & 63;
  const int wr   = (wid & 1) << 6;
  const int wc   = (wid >> 1) << 6;
  const int lrow = lane & 15;
  const int lk   = (((lane >> 4) ^ ((lrow >> 1) & 3)) << 3);
  const int srow = wid * 32 + (lane >> 2);
  const int skol = (((lane & 3) ^ ((lane >> 3) & 3)) << 3);

  const f32x4 zero = {0.f, 0.f, 0.f, 0.f};
#pragma unroll
  for (int i = 0; i < 4; ++i)
#pragma unroll
    for (int j = 0; j < 4; ++j) acc[i][j] = zero;

  for (int kb = 0; kb < kmax; kb += 64) {
#pragma unroll
    for (int h = 0; h < 2; ++h)
#pragma unroll
      for (int t = 0; t < 2; ++t) {
        const size_t ga = (size_t)(rowBlock + srow + t * 16) * lda + kb + h * 32 + skol;
        const size_t gb = (size_t)(colBlock + srow + t * 16) * ldb + kb + h * 32 + skol;
        const int lo = h * 4096 + (wid * 32 + t * 16) * 32;
        g2l16(Ah + ga, &Als[lo]);
        g2l16(Bh + gb, &Bls[lo]);
      }
    __syncthreads();

#pragma unroll
    for (int h = 0; h < 2; ++h) {
      bf16x8 ah[4], bh[4];
#pragma unroll
      for (int r = 0; r < 4; ++r) {
        ah[r] = *(const bf16x8*)&Als[h * 4096 + (wr + r * 16 + lrow) * 32 + lk];
        bh[r] = *(const bf16x8*)&Bls[h * 4096 + (wc + r * 16 + lrow) * 32 + lk];
      }
#pragma unroll
      for (int r = 0; r < 4; ++r)
#pragma unroll
        for (int c = 0; c < 4; ++c)
          acc[r][c] = MFMA16(ah[r], bh[c], acc[r][c]);
    }
    __syncthreads();
  }
}

// ---------------- fused split/transpose preprocessing (unchanged) ----------------
__global__ __launch_bounds__(256) void k_split_all(
    const float* __restrict__ X, u16* __restrict__ Xh, u16* __restrict__ Xl,
    const float* __restrict__ Wq, const float* __restrict__ Wk, const float* __restrict__ Wv,
    u16* __restrict__ Wqh, u16* __restrict__ Wql,
    u16* __restrict__ Wkh, u16* __restrict__ Wkl, u16* __restrict__ Wvh) {
  __shared__ float t[64][65];
  const int bid = blockIdx.x;
  const int tid = threadIdx.x;
  const int wid = tid >> 6, lane = tid & 63;

  if (bid < 4096) {
    const int kt16 = bid & 127;
    const int rt32 = (bid >> 7) * 4 + wid;
    const int row = rt32 * 32 + (lane & 31);
    const int col = kt16 * 16 + ((lane >> 5) << 3);
    const float* src = X + (size_t)row * DM + col;
    const float4 v0 = *(const float4*)src;
    const float4 v1 = *(const float4*)(src + 4);
    float v[8] = {v0.x, v0.y, v0.z, v0.w, v1.x, v1.y, v1.z, v1.w};
    u16 h[8], l[8];
#pragma unroll
    for (int j = 0; j < 8; ++j) {
      h[j] = f2bf(v[j]);
      l[j] = f2bf(v[j] - bf2f(h[j]));
    }
    u16* hp = Xh + (size_t)row * DM + col;
    *(ushort4*)hp = *(ushort4*)&h[0];
    *(ushort4*)(hp + 4) = *(ushort4*)&h[4];
    u16* lp = Xl + (((size_t)rt32 * 128 + kt16) * 64 + lane) * 8;
    *(ushort4*)lp = *(ushort4*)&l[0];
    *(ushort4*)(lp + 4) = *(ushort4*)&l[4];
    return;
  }

  const int r = bid - 4096;
  const int z = r >> 10;
  const int rem = r & 1023;
  const int n0 = (rem & 31) * 64, k0 = (rem >> 5) * 64;
  const float* W = (z == 0) ? Wq : (z == 1) ? Wk : Wv;
  u16* Oh = (z == 0) ? Wqh : (z == 1) ? Wkh : Wvh;
  u16* Ol = (z == 0) ? Wql : Wkl;
  const int tx = tid & 63, ty = tid >> 6;
#pragma unroll
  for (int i = 0; i < 16; ++i)
    t[ty * 16 + i][tx] = W[(size_t)(k0 + ty * 16 + i) * DM + n0 + tx];
  __syncthreads();
  {
    const int nl = tid >> 2, kc = (tid & 3) * 16;
    u16 h[16];
#pragma unroll
    for (int i = 0; i < 16; ++i) h[i] = f2bf(t[kc + i][nl]);
    u16* hp = Oh + (size_t)(n0 + nl) * DM + k0 + kc;
#pragma unroll
    for (int i = 0; i < 4; ++i) *(ushort4*)(hp + i * 4) = *(ushort4*)&h[i * 4];
  }
  if (z < 2) {
#pragma unroll
    for (int tt = 0; tt < 2; ++tt) {
      const int idx = wid * 2 + tt;
      const int rt = idx >> 2, kt = idx & 3;
      const int nl = rt * 32 + (lane & 31);
      const int kc = kt * 16 + ((lane >> 5) << 3);
      u16 l[8];
#pragma unroll
      for (int j = 0; j < 8; ++j) {
        const float v = t[kc + j][nl];
        l[j] = f2bf(v - bf2f(f2bf(v)));
      }
      const int rtg = (n0 >> 5) + rt, ktg = (k0 >> 4) + kt;
      u16* lp = Ol + (((size_t)rtg * (DM / 16) + ktg) * 64 + lane) * 8;
      *(ushort4*)lp = *(ushort4*)&l[0];
      *(ushort4*)(lp + 4) = *(ushort4*)&l[4];
    }
  }
}

// ---------------------------------------------------------------------------
// Q/K projection, round 4: 128x256 tile, 8 waves, BK=16, all-FT32 LDS.
// 64 KB LDS/block -> 2 blocks/CU co-resident (4 waves/SIMD) to fill stalls.
// Per K-tile: 3 g2l16 (pre-swizzled gathers), 8 lane-linear ds_read_b128,
// 12 MFMA32, one vmcnt(0) drain + one barrier (round-2 proven skeleton).
// LDS map/buf (u16): A-hi[rt*512] 0..2048 | A-lo 2048..4096 |
//                    B-hi[ct*512] 4096..8192 | B-lo 8192..12288. dbuf at 12288.
// ---------------------------------------------------------------------------
__global__ __launch_bounds__(512, 4) void k_proj_qk(
    const u16* __restrict__ Xh, const u16* __restrict__ Xl,
    const u16* __restrict__ Wqh, const u16* __restrict__ Wql,
    const u16* __restrict__ Wkh, const u16* __restrict__ Wkl,
    u16* __restrict__ Qh, u16* __restrict__ Ql,
    u16* __restrict__ Kh, u16* __restrict__ Kl, float rscaleQ)
{
  __shared__ __align__(16) u16 smem[32768];     // 64 KiB (dbuf 48K + epi scratch)
  const int z = blockIdx.z;
  const u16* __restrict__ Bw = z ? Wkh : Wqh;
  const u16* __restrict__ Blg = z ? Wkl : Wql;
  u16* __restrict__ Oh = z ? Kh : Qh;
  u16* __restrict__ Ol = z ? Kl : Ql;
  const float rs = z ? 1.0f : rscaleQ;

  const int rowBlock = blockIdx.y * 128;        // 32 row blocks
  const int colBlock = blockIdx.x * 256;        // 8 col blocks
  const int tid  = threadIdx.x;
  const int wid  = tid >> 6, lane = tid & 63;
  const int wm   = wid >> 2, wn = wid & 3;      // 2x4 waves, 64x64 out each
  const int l31  = lane & 31, lh = lane >> 5;

  // running global source pointers (advance by one k16 per tile)
  const u16* srcA;                              // waves 0-3: A-hi gather; 4-7: A-lo
  size_t stepA;
  if (wid < 4) {
    srcA  = Xh + (size_t)(rowBlock + wid * 32 + l31) * DM + lh * 8;
    stepA = 16;
  } else {
    srcA  = Xl + (size_t)((rowBlock >> 5) + (wid - 4)) * 128 * 512 + lane * 8;
    stepA = 512;
  }
  const u16* srcBh = Bw  + (size_t)(colBlock + wid * 32 + l31) * DM + lh * 8;
  const u16* srcBl = Blg + (size_t)((colBlock >> 5) + wid) * 128 * 512 + lane * 8;

  f32x16 acc[2][2];
  {
    const f32x16 z16 = {0.f,0.f,0.f,0.f,0.f,0.f,0.f,0.f,0.f,0.f,0.f,0.f,0.f,0.f,0.f,0.f};
#pragma unroll
    for (int r = 0; r < 2; ++r)
#pragma unroll
      for (int c = 0; c < 2; ++c) acc[r][c] = z16;
  }

#define P_STG(bufN) { \
    g2l16(srcA,  &smem[(bufN) + tid * 8]); \
    g2l16(srcBh, &smem[(bufN) + 4096 + tid * 8]); \
    g2l16(srcBl, &smem[(bufN) + 8192 + tid * 8]); \
    srcA += stepA; srcBh += 16; srcBl += 512; }

#define P_PH(bufC) { \
    bf16x8 ah[2], bh[2], al[2], bl[2]; \
    _Pragma("unroll") for (int r_ = 0; r_ < 2; ++r_) { \
      ah[r_] = *(const bf16x8*)&smem[(bufC) + (wm*2 + r_)*512 + lane*8]; \
      al[r_] = *(const bf16x8*)&smem[(bufC) + 2048 + (wm*2 + r_)*512 + lane*8]; } \
    _Pragma("unroll") for (int c_ = 0; c_ < 2; ++c_) { \
      bh[c_] = *(const bf16x8*)&smem[(bufC) + 4096 + (wn*2 + c_)*512 + lane*8]; \
      bl[c_] = *(const bf16x8*)&smem[(bufC) + 8192 + (wn*2 + c_)*512 + lane*8]; } \
    __builtin_amdgcn_s_setprio(1); \
    _Pragma("unroll") for (int r_ = 0; r_ < 2; ++r_) \
      _Pragma("unroll") for (int c_ = 0; c_ < 2; ++c_) { \
        acc[r_][c_] = MFMA32(ah[r_], bh[c_], acc[r_][c_]); \
        acc[r_][c_] = MFMA32(ah[r_], bl[c_], acc[r_][c_]); \
        acc[r_][c_] = MFMA32(al[r_], bh[c_], acc[r_][c_]); } \
    __builtin_amdgcn_s_setprio(0); }

  // prologue: stage tile 0
  P_STG(0)
  asm volatile("s_waitcnt vmcnt(0)" ::: "memory");
  __builtin_amdgcn_s_barrier();

  for (int t = 0; t < 128; ++t) {
    const int bufC = (t & 1) * 12288;
    const int bufN = bufC ^ 12288;
    if (t < 127) P_STG(bufN)
    __builtin_amdgcn_sched_barrier(0);
    P_PH(bufC)
    asm volatile("s_waitcnt vmcnt(0)" ::: "memory");
    __builtin_amdgcn_s_barrier();
  }
#undef P_PH
#undef P_STG

  // epilogue: hi -> row-major global; lo -> per-wave LDS scratch -> FT32 global
  __syncthreads();                              // main buffers become scratch
  u16* scr = smem + wid * 4096;                 // 64x64 u16 per wave (8 KiB)
  const int r0g = rowBlock + wm * 64;
  const int c0g = colBlock + wn * 64;
#pragma unroll
  for (int r = 0; r < 2; ++r)
#pragma unroll
    for (int c = 0; c < 2; ++c) {
      const int colL = c * 32 + l31;
#pragma unroll
      for (int g = 0; g < 4; ++g)
#pragma unroll
        for (int e = 0; e < 4; ++e) {
          const int rowL = r * 32 + 8 * g + 4 * lh + e;
          const float v = acc[r][c][g * 4 + e] * rs;
          const u16 h = f2bf(v);
          Oh[(size_t)(r0g + rowL) * DM + c0g + colL] = h;
          scr[rowL * 64 + (((colL >> 3) ^ (rowL & 7)) << 3) + (colL & 7)] =
              f2bf(v - bf2f(h));
        }
    }
  asm volatile("s_waitcnt lgkmcnt(0)" ::: "memory");
  __builtin_amdgcn_sched_barrier(0);
#pragma unroll
  for (int rt = 0; rt < 2; ++rt)
#pragma unroll
    for (int kt = 0; kt < 4; ++kt) {
      const int rowL = rt * 32 + l31;
      const int cl2 = kt * 2 + lh;
      const bf16x8 v = *(const bf16x8*)&scr[rowL * 64 + ((cl2 ^ (rowL & 7)) << 3)];
      const int rtg = (rowBlock >> 5) + wm * 2 + rt;
      const int ktg = (colBlock >> 4) + wn * 4 + kt;
      *(bf16x8*)(Ol + (((size_t)rtg * 128 + ktg) * 64 + lane) * 8) = v;
    }
}

// ---------------------------------------------------------------------------
// V projection (unchanged).
// ---------------------------------------------------------------------------
__global__ __launch_bounds__(512, 2) void k_proj_v(
    const u16* __restrict__ Xh, const u16* __restrict__ Wvh, u16* __restrict__ Vt)
{
  __shared__ __align__(16) u16 smem[49152];     // 96 KiB: 2 x (A 32KB + B 16KB)
  const int rowBlock = blockIdx.y * 256;
  const int colBlock = blockIdx.x * 128;
  const int tid  = threadIdx.x;
  const int wid  = tid >> 6, lane = tid & 63;
  const int wm   = wid >> 1, wn = wid & 1;      // wave tile: 64 rows x 64 cols
  const int l31  = lane & 31, lh = lane >> 5;
  const int srow = tid >> 2, schunk = tid & 3;
  const int sko  = ((schunk ^ ((srow >> 1) & 3)) << 3);
  const int rkey = (l31 >> 1) & 3;

  f32x16 acc[2][2];
  {
    const f32x16 z16 = {0.f,0.f,0.f,0.f,0.f,0.f,0.f,0.f,0.f,0.f,0.f,0.f,0.f,0.f,0.f,0.f};
#pragma unroll
    for (int r = 0; r < 2; ++r)
#pragma unroll
      for (int c = 0; c < 2; ++c) acc[r][c] = z16;
  }

#define V_STGA(hh, pp) g2l16(Xh + (size_t)(rowBlock + (pp)*128 + srow) * DM + kbn + (hh)*32 + sko, \
                             &smem[bufN + (hh)*8192 + (pp)*4096 + tid*8]);
#define V_STGB(hh)     g2l16(Wvh + (size_t)(colBlock + srow) * DM + kbn + (hh)*32 + sko, \
                             &smem[bufN + 16384 + (hh)*4096 + tid*8]);

#define V_PH(qq, STMT) { \
    __builtin_amdgcn_sched_barrier(0); \
    STMT; \
    bf16x8 ah[2], bh[2]; \
    const int cl_ = ((qq) & 1) * 2 + lh; \
    const int hx_ = (qq) >> 1; \
    _Pragma("unroll") for (int r_ = 0; r_ < 2; ++r_) \
      ah[r_] = *(const bf16x8*)&smem[bufC + ((hx_*256 + wm*64 + r_*32 + l31) << 5) + ((cl_ ^ rkey) << 3)]; \
    _Pragma("unroll") for (int c_ = 0; c_ < 2; ++c_) \
      bh[c_] = *(const bf16x8*)&smem[bufC + 16384 + ((hx_*128 + wn*64 + c_*32 + l31) << 5) + ((cl_ ^ rkey) << 3)]; \
    __builtin_amdgcn_s_setprio(1); \
    _Pragma("unroll") for (int r_ = 0; r_ < 2; ++r_) \
      _Pragma("unroll") for (int c_ = 0; c_ < 2; ++c_) \
        acc[r_][c_] = MFMA32(ah[r_], bh[c_], acc[r_][c_]); \
    __builtin_amdgcn_s_setprio(0); }

  {
    const size_t kbn = 0; const int bufN = 0;
    V_STGA(0,0) V_STGA(0,1) V_STGA(1,0) V_STGA(1,1) V_STGB(0) V_STGB(1)
  }
  asm volatile("s_waitcnt vmcnt(0)" ::: "memory");
  __builtin_amdgcn_s_barrier();

  for (int t = 0; t < 32; ++t) {
    const int bufC = (t & 1) * 24576;
    const int bufN = bufC ^ 24576;
    const size_t kbn = (size_t)(t + 1) * 64;
    const bool more = (t < 31);
    V_PH(0, if (more) { V_STGA(0,0) V_STGA(0,1) V_STGB(0) })
    V_PH(1, if (more) { V_STGA(1,0) V_STGA(1,1) V_STGB(1) })
    V_PH(2, ;)
    V_PH(3, ;)
    asm volatile("s_waitcnt vmcnt(0)" ::: "memory");
    __builtin_amdgcn_s_barrier();
  }
#undef V_PH
#undef V_STGB
#undef V_STGA

  // epilogue: transposed store Vt[col][row], 4 consecutive rows packed
  const int vr0 = rowBlock + wm * 64;
#pragma unroll
  for (int r = 0; r < 2; ++r)
#pragma unroll
    for (int c = 0; c < 2; ++c) {
      const int col = colBlock + wn * 64 + c * 32 + l31;
#pragma unroll
      for (int g = 0; g < 4; ++g) {
        ushort4 pk;
        pk.x = f2bf(acc[r][c][g * 4 + 0]);
        pk.y = f2bf(acc[r][c][g * 4 + 1]);
        pk.z = f2bf(acc[r][c][g * 4 + 2]);
        pk.w = f2bf(acc[r][c][g * 4 + 3]);
        *(ushort4*)(Vt + (size_t)col * SEQ + vr0 + r * 32 + 8 * g + 4 * lh) = pk;
      }
    }
}

// ---------------------------------------------------------------------------
// S = (Q/scale) @ K^T, round 4: 128x128 triangle tiles (528 blocks), 4 waves,
// BK=16, all-FT32 LDS, 32 KB/block -> 3-4 blocks/CU co-resident.
// LDS map/buf (u16): A-hi 0..2048 | A-lo 2048..4096 | B-hi 4096..6144 |
//                    B-lo 6144..8192. dbuf at 8192.
// ---------------------------------------------------------------------------
__global__ __launch_bounds__(256, 4) void k_scores(
    const u16* __restrict__ Qh, const u16* __restrict__ Ql,
    const u16* __restrict__ Kh, const u16* __restrict__ Kl, float* __restrict__ S)
{
  __shared__ __align__(16) u16 smem[16384];     // 32 KiB
  const int bid = blockIdx.x;
  int by = (int)((sqrtf(8.0f * (float)bid + 1.0f) - 1.0f) * 0.5f);
  while ((by + 1) * (by + 2) / 2 <= bid) ++by;
  while (by * (by + 1) / 2 > bid) --by;
  const int bx = bid - by * (by + 1) / 2;
  const int rowBlock = by * 128, colBlock = bx * 128;

  const int tid  = threadIdx.x;
  const int wid  = tid >> 6, lane = tid & 63;
  const int wm   = wid >> 1, wn = wid & 1;      // 2x2 waves, 64x64 out each
  const int l31  = lane & 31, lh = lane >> 5;

  const u16* srcAh = Qh + (size_t)(rowBlock + wid * 32 + l31) * DM + lh * 8;
  const u16* srcAl = Ql + (size_t)((rowBlock >> 5) + wid) * 128 * 512 + lane * 8;
  const u16* srcBh = Kh + (size_t)(colBlock + wid * 32 + l31) * DM + lh * 8;
  const u16* srcBl = Kl + (size_t)((colBlock >> 5) + wid) * 128 * 512 + lane * 8;

  f32x16 acc[2][2];
  {
    const f32x16 z16 = {0.f,0.f,0.f,0.f,0.f,0.f,0.f,0.f,0.f,0.f,0.f,0.f,0.f,0.f,0.f,0.f};
#pragma unroll
    for (int r = 0; r < 2; ++r)
#pragma unroll
      for (int c = 0; c < 2; ++c) acc[r][c] = z16;
  }

#define S_STG(bufN) { \
    g2l16(srcAh, &smem[(bufN) + tid * 8]); \
    g2l16(srcAl, &smem[(bufN) + 2048 + tid * 8]); \
    g2l16(srcBh, &smem[(bufN) + 4096 + tid * 8]); \
    g2l16(srcBl, &smem[(bufN) + 6144 + tid * 8]); \
    srcAh += 16; srcAl += 512; srcBh += 16; srcBl += 512; }

#define S_PH(bufC) { \
    bf16x8 ah[2], bh[2], al[2], bl[2]; \
    _Pragma("unroll") for (int r_ = 0; r_ < 2; ++r_) { \
      ah[r_] = *(const bf16x8*)&smem[(bufC) + (wm*2 + r_)*512 + lane*8]; \
      al[r_] = *(const bf16x8*)&smem[(bufC) + 2048 + (wm*2 + r_)*512 + lane*8]; } \
    _Pragma("unroll") for (int c_ = 0; c_ < 2; ++c_) { \
      bh[c_] = *(const bf16x8*)&smem[(bufC) + 4096 + (wn*2 + c_)*512 + lane*8]; \
      bl[c_] = *(const bf16x8*)&smem[(bufC) + 6144 + (wn*2 + c_)*512 + lane*8]; } \
    __builtin_amdgcn_s_setprio(1); \
    _Pragma("unroll") for (int r_ = 0; r_ < 2; ++r_) \
      _Pragma("unroll") for (int c_ = 0; c_ < 2; ++c_) { \
        acc[r_][c_] = MFMA32(ah[r_], bh[c_], acc[r_][c_]); \
        acc[r_][c_] = MFMA32(ah[r_], bl[c_], acc[r_][c_]); \
        acc[r_][c_] = MFMA32(al[r_], bh[c_], acc[r_][c_]); } \
    __builtin_amdgcn_s_setprio(0); }

  S_STG(0)
  asm volatile("s_waitcnt vmcnt(0)" ::: "memory");
  __builtin_amdgcn_s_barrier();

  for (int t = 0; t < 128; ++t) {
    const int bufC = (t & 1) * 8192;
    const int bufN = bufC ^ 8192;
    if (t < 127) S_STG(bufN)
    __builtin_amdgcn_sched_barrier(0);
    S_PH(bufC)
    asm volatile("s_waitcnt vmcnt(0)" ::: "memory");
    __builtin_amdgcn_s_barrier();
  }
#undef S_PH
#undef S_STG

  const int r0 = rowBlock + wm * 64, c0 = colBlock + wn * 64;
#pragma unroll
  for (int r = 0; r < 2; ++r)
#pragma unroll
    for (int c = 0; c < 2; ++c) {
      const int col = c0 + c * 32 + l31;
#pragma unroll
      for (int g = 0; g < 4; ++g)
#pragma unroll
        for (int e = 0; e < 4; ++e) {
          const int row = r0 + r * 32 + 8 * g + 4 * lh + e;
          S[(size_t)row * SEQ + col] = acc[r][c][g * 4 + e];
        }
    }
}

// Row softmax (causal) + inverted dropout; S fp32 -> P bf16 (zero-padded to 128).
__global__ __launch_bounds__(256) void k_softmax_dropout(const float* __restrict__ S,
                                                         u16* __restrict__ P) {
  const int row = blockIdx.x;
  const int n = row + 1;
  const int nt = (n + 1023) >> 10;
  const int tid = threadIdx.x;
  __shared__ float buf[SEQ];
  __shared__ float red[4];
  __shared__ float bcast;
  const float* srow = S + (size_t)row * SEQ;

  float lmax = -INFINITY;
  for (int t = 0; t < nt; ++t) {
    int j4 = tid + t * 256;
    float4 v = *(const float4*)(srow + (size_t)j4 * 4);
    int b = j4 * 4;
    float x0 = (b + 0 < n) ? v.x : -INFINITY;
    float x1 = (b + 1 < n) ? v.y : -INFINITY;
    float x2 = (b + 2 < n) ? v.z : -INFINITY;
    float x3 = (b + 3 < n) ? v.w : -INFINITY;
    buf[b + 0] = x0; buf[b + 1] = x1; buf[b + 2] = x2; buf[b + 3] = x3;
    lmax = fmaxf(lmax, fmaxf(fmaxf(x0, x1), fmaxf(x2, x3)));
  }
  for (int off = 32; off > 0; off >>= 1) lmax = fmaxf(lmax, __shfl_down(lmax, off, 64));
  if ((tid & 63) == 0) red[tid >> 6] = lmax;
  __syncthreads();
  if (tid == 0) bcast = fmaxf(fmaxf(red[0], red[1]), fmaxf(red[2], red[3]));
  __syncthreads();
  const float m = bcast;

  float lsum = 0.f;
  for (int t = 0; t < nt; ++t) {
    int b = (tid + t * 256) * 4;
    float e0 = expf(buf[b + 0] - m);
    float e1 = expf(buf[b + 1] - m);
    float e2 = expf(buf[b + 2] - m);
    float e3 = expf(buf[b + 3] - m);
    buf[b + 0] = e0; buf[b + 1] = e1; buf[b + 2] = e2; buf[b + 3] = e3;
    lsum += (e0 + e1) + (e2 + e3);
  }
  for (int off = 32; off > 0; off >>= 1) lsum += __shfl_down(lsum, off, 64);
  if ((tid & 63) == 0) red[tid >> 6] = lsum;
  __syncthreads();
  if (tid == 0) bcast = (red[0] + red[1]) + (red[2] + red[3]);
  __syncthreads();
  const float total = bcast;

  u16* prow = P + (size_t)row * SEQ;
  const int zeroEnd = ((row >> 7) + 1) << 7;
  for (int j = tid; j < zeroEnd; j += 256) {
    float out = 0.f;
    if (j < n) {
      const float w = buf[j] / total;
      out = dropout_keep((u32)(row * SEQ + j)) ? w * 2.0f : 0.f;
    }
    prow[j] = f2bf(out);
  }
}

// context = P @ V (plain bf16, causal-truncated K-loop), fp32 out; heavy rows first.
__global__ __launch_bounds__(256) void k_pv(const u16* __restrict__ P,
                                            const u16* __restrict__ Vt,
                                            float* __restrict__ O) {
  __shared__ __align__(16) u16 smem[16384];
  const int by = (SEQ / 128 - 1) - blockIdx.y;
  f32x4 acc[4][4];
  gemm_core(P, Vt, SEQ, SEQ, by * 128, blockIdx.x * 128, (by + 1) * 128, acc, smem);

  const int lane = threadIdx.x & 63, wid = threadIdx.x >> 6;
  const int r0 = by * 128 + ((wid & 1) << 6) + ((lane >> 4) << 2);
  const int c0 = blockIdx.x * 128 + ((wid >> 1) << 6) + (lane & 15);
#pragma unroll
  for (int r = 0; r < 4; ++r)
#pragma unroll
    for (int c = 0; c < 4; ++c)
#pragma unroll
      for (int e = 0; e < 4; ++e)
        O[(size_t)(r0 + r * 16 + e) * DM + (c0 + c * 16)] = acc[r][c][e];
}

extern "C" void kernel_launch(void* const* d_in, const int* in_sizes, int n_in,
                              void* d_out, int out_size, void* d_ws, size_t ws_size,
                              hipStream_t stream) {
  const float* x  = (const float*)d_in[0];
  const float* Wq = (const float*)d_in[1];
  const float* Wk = (const float*)d_in[2];
  const float* Wv = (const float*)d_in[3];

  // workspace layout (u16 elements; <=152 MiB). FT32 planes same sizes as before.
  const size_t PL = (size_t)SEQ * DM;   // 16 MiB/plane
  const size_t WL = (size_t)DM * DM;    // 8 MiB/plane
  u16* base = (u16*)d_ws;
  u16* Qh = base;                // [SEQ][DM] row-major
  u16* Ql = Qh + PL;             // FT32
  u16* Kh = Ql + PL;             // row-major
  u16* Kl = Kh + PL;             // FT32
  u16* Vt = Kl + PL;             // [DM][SEQ]
  u16* P  = base;                // [SEQ][SEQ] bf16, overlays Qh+Ql (dead by then)
  u16* regA = Vt + PL;           // offset 80 MiB
  u16* Xh  = regA;               // [SEQ][DM] row-major
  u16* Xl  = Xh + PL;            // FT32
  u16* Wqh = Xl + PL;            // [DM][DM] transposed row-major
  u16* Wql = Wqh + WL;           // FT32
  u16* Wkh = Wql + WL;
  u16* Wkl = Wkh + WL;
  u16* Wvh = Wkl + WL;
  float* S = (float*)regA;       // [SEQ][SEQ] fp32 overlays Xh..Wkl (dead when
                                 // k_scores runs; Wvh sits just past S's end)

  const float rscale = 1.0f / sqrtf(2048.0f);
  k_split_all<<<dim3(4096 + 3 * 1024), dim3(256), 0, stream>>>(
      x, Xh, Xl, Wq, Wk, Wv, Wqh, Wql, Wkh, Wkl, Wvh);
  k_proj_qk<<<dim3(DM / 256, SEQ / 128, 2), dim3(512), 0, stream>>>(
      Xh, Xl, Wqh, Wql, Wkh, Wkl, Qh, Ql, Kh, Kl, rscale);
  k_proj_v<<<dim3(DM / 128, SEQ / 256), dim3(512), 0, stream>>>(Xh, Wvh, Vt);
  k_scores<<<dim3((SEQ / 128) * (SEQ / 128 + 1) / 2), dim3(256), 0, stream>>>(
      Qh, Ql, Kh, Kl, S);
  k_softmax_dropout<<<dim3(SEQ), dim3(256), 0, stream>>>(S, P);
  k_pv<<<dim3(DM / 128, SEQ / 128), dim3(256), 0, stream>>>(P, Vt, (float*)d_out);
}

// Round 5
// 570.267 us; speedup vs baseline: 1.1287x; 1.1287x over previous
//
#include <hip/hip_runtime.h>
#include <cstdint>
#include <cstddef>
#include <cmath>

#define SEQ 4096
#define DM  2048

typedef unsigned int u32;
typedef unsigned short u16;
typedef __attribute__((ext_vector_type(8))) short bf16x8;
typedef __attribute__((ext_vector_type(4))) float f32x4;
typedef __attribute__((ext_vector_type(16))) float f32x16;

// ---------------- bf16 helpers (RNE) ----------------
__device__ __forceinline__ u16 f2bf(float f) {
  u32 u = __float_as_uint(f);
  return (u16)((u + 0x7FFFu + ((u >> 16) & 1u)) >> 16);
}
__device__ __forceinline__ float bf2f(u16 h) { return __uint_as_float(((u32)h) << 16); }

// packed causal S layout: row band b = row>>7 has padded length 128*(b+1).
// base(row) = 8192*b*(b+1) + 128*(row&127)*(b+1). total 8.65M floats (34.6MB).
__device__ __forceinline__ size_t s_base(int row) {
  const int b = row >> 7;
  return (size_t)8192 * b * (b + 1) + (size_t)128 * (row & 127) * (b + 1);
}

// ---------------- threefry dropout (verified round 1, variant 0) ----------------
__device__ __forceinline__ u32 rotl32(u32 x, int r) { return (x << r) | (x >> (32 - r)); }

__device__ __forceinline__ void tf2x32(u32 c0, u32 c1, u32& o0, u32& o1) {
  const u32 k0 = 0u, k1 = 42u, k2 = 0x1BD11BDAu ^ 0u ^ 42u;
  u32 x0 = c0 + k0;
  u32 x1 = c1 + k1;
#define TFR(r) { x0 += x1; x1 = rotl32(x1, (r)); x1 ^= x0; }
  TFR(13) TFR(15) TFR(26) TFR(6)   x0 += k1; x1 += k2 + 1u;
  TFR(17) TFR(29) TFR(16) TFR(24)  x0 += k2; x1 += k0 + 2u;
  TFR(13) TFR(15) TFR(26) TFR(6)   x0 += k0; x1 += k1 + 3u;
  TFR(17) TFR(29) TFR(16) TFR(24)  x0 += k1; x1 += k2 + 4u;
  TFR(13) TFR(15) TFR(26) TFR(6)   x0 += k2; x1 += k0 + 5u;
#undef TFR
  o0 = x0; o1 = x1;
}

__device__ __forceinline__ bool dropout_keep(u32 idx) {
  u32 a, b; tf2x32(0u, idx, a, b);
  return (((a ^ b) & 0x80000000u) == 0u);
}

// ---------------- async global -> LDS, 16 B/lane ----------------
__device__ __forceinline__ void g2l16(const void* g, void* l) {
  __builtin_amdgcn_global_load_lds((const __attribute__((address_space(1))) u32*)g,
                                   (__attribute__((address_space(3))) u32*)l, 16, 0, 0);
}

#define MFMA16(a, b, c) __builtin_amdgcn_mfma_f32_16x16x32_bf16(a, b, c, 0, 0, 0)
#define MFMA32(a, b, c) __builtin_amdgcn_mfma_f32_32x32x16_bf16(a, b, c, 0, 0, 0)

// FT32 layout (for 32x32x16 A/B operands) of [R rows][K k]:
// tile = 32 rows x 16 k; elem (rt, kt, lane, j) at (((rt*(K/16)+kt)*64+lane)*8+j)
// where lane holds row rt*32+(lane&31), k = kt*16+(lane>>5)*8+j.

// Plain bf16 GEMM core, 16x16x32, BK=64 (kept for k_pv): C = A * B^T.
__device__ __forceinline__ void gemm_core(
    const u16* __restrict__ Ah, const u16* __restrict__ Bh,
    int lda, int ldb, int rowBlock, int colBlock, int kmax,
    f32x4 (&acc)[4][4], u16* smem)
{
  u16* Als = smem;
  u16* Bls = smem + 8192;
  const int tid  = threadIdx.x;
  const int wid  = tid >> 6;
  const int lane = tid & 63;
  const int wr   = (wid & 1) << 6;
  const int wc   = (wid >> 1) << 6;
  const int lrow = lane & 15;
  const int lk   = (((lane >> 4) ^ ((lrow >> 1) & 3)) << 3);
  const int srow = wid * 32 + (lane >> 2);
  const int skol = (((lane & 3) ^ ((lane >> 3) & 3)) << 3);

  const f32x4 zero = {0.f, 0.f, 0.f, 0.f};
#pragma unroll
  for (int i = 0; i < 4; ++i)
#pragma unroll
    for (int j = 0; j < 4; ++j) acc[i][j] = zero;

  for (int kb = 0; kb < kmax; kb += 64) {
#pragma unroll
    for (int h = 0; h < 2; ++h)
#pragma unroll
      for (int t = 0; t < 2; ++t) {
        const size_t ga = (size_t)(rowBlock + srow + t * 16) * lda + kb + h * 32 + skol;
        const size_t gb = (size_t)(colBlock + srow + t * 16) * ldb + kb + h * 32 + skol;
        const int lo = h * 4096 + (wid * 32 + t * 16) * 32;
        g2l16(Ah + ga, &Als[lo]);
        g2l16(Bh + gb, &Bls[lo]);
      }
    __syncthreads();

#pragma unroll
    for (int h = 0; h < 2; ++h) {
      bf16x8 ah[4], bh[4];
#pragma unroll
      for (int r = 0; r < 4; ++r) {
        ah[r] = *(const bf16x8*)&Als[h * 4096 + (wr + r * 16 + lrow) * 32 + lk];
        bh[r] = *(const bf16x8*)&Bls[h * 4096 + (wc + r * 16 + lrow) * 32 + lk];
      }
#pragma unroll
      for (int r = 0; r < 4; ++r)
#pragma unroll
        for (int c = 0; c < 4; ++c)
          acc[r][c] = MFMA16(ah[r], bh[c], acc[r][c]);
    }
    __syncthreads();
  }
}

// ---------------- fused split/transpose preprocessing (unchanged) ----------------
__global__ __launch_bounds__(256) void k_split_all(
    const float* __restrict__ X, u16* __restrict__ Xh, u16* __restrict__ Xl,
    const float* __restrict__ Wq, const float* __restrict__ Wk, const float* __restrict__ Wv,
    u16* __restrict__ Wqh, u16* __restrict__ Wql,
    u16* __restrict__ Wkh, u16* __restrict__ Wkl, u16* __restrict__ Wvh) {
  __shared__ float t[64][65];
  const int bid = blockIdx.x;
  const int tid = threadIdx.x;
  const int wid = tid >> 6, lane = tid & 63;

  if (bid < 4096) {
    const int kt16 = bid & 127;
    const int rt32 = (bid >> 7) * 4 + wid;
    const int row = rt32 * 32 + (lane & 31);
    const int col = kt16 * 16 + ((lane >> 5) << 3);
    const float* src = X + (size_t)row * DM + col;
    const float4 v0 = *(const float4*)src;
    const float4 v1 = *(const float4*)(src + 4);
    float v[8] = {v0.x, v0.y, v0.z, v0.w, v1.x, v1.y, v1.z, v1.w};
    u16 h[8], l[8];
#pragma unroll
    for (int j = 0; j < 8; ++j) {
      h[j] = f2bf(v[j]);
      l[j] = f2bf(v[j] - bf2f(h[j]));
    }
    u16* hp = Xh + (size_t)row * DM + col;
    *(ushort4*)hp = *(ushort4*)&h[0];
    *(ushort4*)(hp + 4) = *(ushort4*)&h[4];
    u16* lp = Xl + (((size_t)rt32 * 128 + kt16) * 64 + lane) * 8;
    *(ushort4*)lp = *(ushort4*)&l[0];
    *(ushort4*)(lp + 4) = *(ushort4*)&l[4];
    return;
  }

  const int r = bid - 4096;
  const int z = r >> 10;
  const int rem = r & 1023;
  const int n0 = (rem & 31) * 64, k0 = (rem >> 5) * 64;
  const float* W = (z == 0) ? Wq : (z == 1) ? Wk : Wv;
  u16* Oh = (z == 0) ? Wqh : (z == 1) ? Wkh : Wvh;
  u16* Ol = (z == 0) ? Wql : Wkl;
  const int tx = tid & 63, ty = tid >> 6;
#pragma unroll
  for (int i = 0; i < 16; ++i)
    t[ty * 16 + i][tx] = W[(size_t)(k0 + ty * 16 + i) * DM + n0 + tx];
  __syncthreads();
  {
    const int nl = tid >> 2, kc = (tid & 3) * 16;
    u16 h[16];
#pragma unroll
    for (int i = 0; i < 16; ++i) h[i] = f2bf(t[kc + i][nl]);
    u16* hp = Oh + (size_t)(n0 + nl) * DM + k0 + kc;
#pragma unroll
    for (int i = 0; i < 4; ++i) *(ushort4*)(hp + i * 4) = *(ushort4*)&h[i * 4];
  }
  if (z < 2) {
#pragma unroll
    for (int tt = 0; tt < 2; ++tt) {
      const int idx = wid * 2 + tt;
      const int rt = idx >> 2, kt = idx & 3;
      const int nl = rt * 32 + (lane & 31);
      const int kc = kt * 16 + ((lane >> 5) << 3);
      u16 l[8];
#pragma unroll
      for (int j = 0; j < 8; ++j) {
        const float v = t[kc + j][nl];
        l[j] = f2bf(v - bf2f(f2bf(v)));
      }
      const int rtg = (n0 >> 5) + rt, ktg = (k0 >> 4) + kt;
      u16* lp = Ol + (((size_t)rtg * (DM / 16) + ktg) * 64 + lane) * 8;
      *(ushort4*)lp = *(ushort4*)&l[0];
      *(ushort4*)(lp + 4) = *(ushort4*)&l[4];
    }
  }
}

// ---------------------------------------------------------------------------
// Q/K projection (round-1 version, best measured 194 us). 256x256 tile, 8
// waves, BK=64, 4 sub-phases/K-tile. hi A/B double-buffered in 128 KiB LDS via
// swizzled global_load_lds; lo (FT32) direct global->VGPR, pipelined one
// k16-chunk ahead. Raw s_barrier + one vmcnt(0) per K-tile.
// ---------------------------------------------------------------------------
__global__ __launch_bounds__(512, 2) void k_proj_qk(
    const u16* __restrict__ Xh, const u16* __restrict__ Xl,
    const u16* __restrict__ Wqh, const u16* __restrict__ Wql,
    const u16* __restrict__ Wkh, const u16* __restrict__ Wkl,
    u16* __restrict__ Qh, u16* __restrict__ Ql,
    u16* __restrict__ Kh, u16* __restrict__ Kl, float rscaleQ)
{
  __shared__ __align__(16) u16 smem[65536];       // 128 KiB
  const int z = blockIdx.z;
  const u16* __restrict__ Bw = z ? Wkh : Wqh;
  const u16* __restrict__ Bl = z ? Wkl : Wql;
  u16* __restrict__ Oh = z ? Kh : Qh;
  u16* __restrict__ Ol = z ? Kl : Ql;
  const float rs = z ? 1.0f : rscaleQ;

  const int rowBlock = blockIdx.y * 256;
  const int colBlock = blockIdx.x * 256;
  const int tid  = threadIdx.x;
  const int wid  = tid >> 6, lane = tid & 63;
  const int wm   = wid >> 2, wn = wid & 3;       // wave tile: 128 rows x 64 cols
  const int l31  = lane & 31, lh = lane >> 5;
  const int srow = tid >> 2, schunk = tid & 3;   // staging: 128 rows / call-site
  const int sko  = ((schunk ^ ((srow >> 1) & 3)) << 3);
  const int rkey = (l31 >> 1) & 3;
  const int rtA0 = (rowBlock >> 5) + wm * 4;
  const int rtB0 = (colBlock >> 5) + wn * 2;

  f32x16 acc[4][2];
  {
    const f32x16 z16 = {0.f,0.f,0.f,0.f,0.f,0.f,0.f,0.f,0.f,0.f,0.f,0.f,0.f,0.f,0.f,0.f};
#pragma unroll
    for (int r = 0; r < 4; ++r)
#pragma unroll
      for (int c = 0; c < 2; ++c) acc[r][c] = z16;
  }
  bf16x8 alo0[4], blo0[2], alo1[4], blo1[2];

#define QK_STG(hh, pp) { \
    g2l16(Xh + (size_t)(rowBlock + (pp)*128 + srow) * DM + kbn + (hh)*32 + sko, \
          &smem[bufN + (hh)*8192 + (pp)*4096 + tid*8]); \
    g2l16(Bw + (size_t)(colBlock + (pp)*128 + srow) * DM + kbn + (hh)*32 + sko, \
          &smem[bufN + 16384 + (hh)*8192 + (pp)*4096 + tid*8]); }

#define QK_LO(AV, BV, kt) { \
    const int kk_ = (kt); \
    _Pragma("unroll") for (int r_ = 0; r_ < 4; ++r_) \
      AV[r_] = *(const bf16x8*)(Xl + (((size_t)(rtA0 + r_) * 128 + kk_) * 64 + lane) * 8); \
    _Pragma("unroll") for (int c_ = 0; c_ < 2; ++c_) \
      BV[c_] = *(const bf16x8*)(Bl + (((size_t)(rtB0 + c_) * 128 + kk_) * 64 + lane) * 8); }

#define QK_PH(qq, ALC, BLC, ALN, BLN, STMT, ktn) { \
    __builtin_amdgcn_sched_barrier(0); \
    QK_LO(ALN, BLN, ktn); \
    __builtin_amdgcn_sched_barrier(0); \
    STMT; \
    bf16x8 ah[4], bh[2]; \
    const int cl_ = ((qq) & 1) * 2 + lh; \
    const int hx_ = (qq) >> 1; \
    _Pragma("unroll") for (int r_ = 0; r_ < 4; ++r_) \
      ah[r_] = *(const bf16x8*)&smem[bufC + ((hx_*256 + wm*128 + r_*32 + l31) << 5) + ((cl_ ^ rkey) << 3)]; \
    _Pragma("unroll") for (int c_ = 0; c_ < 2; ++c_) \
      bh[c_] = *(const bf16x8*)&smem[bufC + 16384 + ((hx_*256 + wn*64 + c_*32 + l31) << 5) + ((cl_ ^ rkey) << 3)]; \
    __builtin_amdgcn_s_setprio(1); \
    _Pragma("unroll") for (int r_ = 0; r_ < 4; ++r_) \
      _Pragma("unroll") for (int c_ = 0; c_ < 2; ++c_) { \
        acc[r_][c_] = MFMA32(ah[r_], bh[c_], acc[r_][c_]); \
        acc[r_][c_] = MFMA32(ah[r_], BLC[c_], acc[r_][c_]); \
        acc[r_][c_] = MFMA32(ALC[r_], bh[c_], acc[r_][c_]); } \
    __builtin_amdgcn_s_setprio(0); }

  // prologue: stage tile 0, prefetch lo chunk 0
  {
    const size_t kbn = 0; const int bufN = 0;
    QK_STG(0,0) QK_STG(0,1) QK_STG(1,0) QK_STG(1,1)
  }
  QK_LO(alo0, blo0, 0);
  asm volatile("s_waitcnt vmcnt(0)" ::: "memory");
  __builtin_amdgcn_s_barrier();

  for (int t = 0; t < 32; ++t) {
    const int bufC = (t & 1) << 15;            // 0 / 32768 (u16 units)
    const int bufN = bufC ^ 32768;
    const size_t kbn = (size_t)(t + 1) * 64;
    const bool more = (t < 31);
    const int g4 = t * 4;
    QK_PH(0, alo0, blo0, alo1, blo1, if (more) { QK_STG(0,0) QK_STG(0,1) }, g4 + 1)
    QK_PH(1, alo1, blo1, alo0, blo0, if (more) { QK_STG(1,0) QK_STG(1,1) }, g4 + 2)
    QK_PH(2, alo0, blo0, alo1, blo1, ;, g4 + 3)
    QK_PH(3, alo1, blo1, alo0, blo0, ;, (g4 + 4 < 128 ? g4 + 4 : 127))
    asm volatile("s_waitcnt vmcnt(0)" ::: "memory");
    __builtin_amdgcn_s_barrier();
  }
#undef QK_PH
#undef QK_LO
#undef QK_STG

  // epilogue: hi -> row-major global; lo -> per-wave LDS scratch -> FT32 global
  __syncthreads();                              // main buffers become scratch
  u16* scr = smem + wid * 8192;                 // 128x64 u16 per wave (16 KiB)
  const int r0g = rowBlock + wm * 128;
  const int c0g = colBlock + wn * 64;
#pragma unroll
  for (int r = 0; r < 4; ++r)
#pragma unroll
    for (int c = 0; c < 2; ++c) {
      const int colL = c * 32 + l31;
#pragma unroll
      for (int g = 0; g < 4; ++g)
#pragma unroll
        for (int e = 0; e < 4; ++e) {
          const int rowL = r * 32 + 8 * g + 4 * lh + e;
          const float v = acc[r][c][g * 4 + e] * rs;
          const u16 h = f2bf(v);
          Oh[(size_t)(r0g + rowL) * DM + c0g + colL] = h;
          scr[rowL * 64 + (((colL >> 3) ^ (rowL & 7)) << 3) + (colL & 7)] =
              f2bf(v - bf2f(h));
        }
    }
  asm volatile("s_waitcnt lgkmcnt(0)" ::: "memory");
  __builtin_amdgcn_sched_barrier(0);
#pragma unroll
  for (int rt = 0; rt < 4; ++rt)
#pragma unroll
    for (int kt = 0; kt < 4; ++kt) {
      const int rowL = rt * 32 + l31;
      const int cl2 = kt * 2 + lh;
      const bf16x8 v = *(const bf16x8*)&scr[rowL * 64 + ((cl2 ^ (rowL & 7)) << 3)];
      const int rtg = (rowBlock >> 5) + wm * 4 + rt;
      const int ktg = (colBlock >> 4) + wn * 4 + kt;
      *(bf16x8*)(Ol + (((size_t)rtg * 128 + ktg) * 64 + lane) * 8) = v;
    }
}

// ---------------------------------------------------------------------------
// Fused kernel: causal scores tiles (bid < 272) + V projection (bid >= 272).
// scores: 256x128 triangle tiles, BK=32 all-LDS split core (round-2 version,
// best measured), writing PACKED causal S. projv: 256x128 plain bf16 -> Vt
// (round-1 version). proj_v blocks pack into scores' second-round idle tail.
// Both paths: 96 KiB LDS, 512 threads, 2 waves/SIMD.
// ---------------------------------------------------------------------------
__device__ __forceinline__ void scores_body(
    const u16* __restrict__ Qh, const u16* __restrict__ Ql,
    const u16* __restrict__ Kh, const u16* __restrict__ Kl,
    float* __restrict__ S, u16* smem)
{
  const int bid = blockIdx.x;
  int by = (int)((sqrtf(4.0f * (float)bid + 1.0f) - 1.0f) * 0.5f);
  while ((by + 1) * (by + 2) <= bid) ++by;
  while (by * (by + 1) > bid) --by;
  const int bx = bid - by * (by + 1);
  const int rowBlock = by * 256, colBlock = bx * 128;

  const int tid  = threadIdx.x;
  const int wid  = tid >> 6, lane = tid & 63;
  const int wm   = wid >> 1, wn = wid & 1;      // wave tile: 64 rows x 64 cols
  const int l31  = lane & 31, lh = lane >> 5;
  const int srow = tid >> 2, schunk = tid & 3;
  const int sko  = ((schunk ^ ((srow >> 1) & 3)) << 3);
  const int rkey = (l31 >> 1) & 3;

  f32x16 acc[2][2];
  {
    const f32x16 z16 = {0.f,0.f,0.f,0.f,0.f,0.f,0.f,0.f,0.f,0.f,0.f,0.f,0.f,0.f,0.f,0.f};
#pragma unroll
    for (int r = 0; r < 2; ++r)
#pragma unroll
      for (int c = 0; c < 2; ++c) acc[r][c] = z16;
  }

// LDS map (u16): Ahi 0 | Bhi 8192 | Alo 12288 | Blo 20480 | size 24576 (48KB), x2
#define S_STG_AHI(pp) g2l16(Qh + (size_t)(rowBlock + (pp)*128 + srow) * DM + kbn + sko, \
                            &smem[bufN + (pp)*4096 + tid*8]);
#define S_STG_BHI     g2l16(Kh + (size_t)(colBlock + srow) * DM + kbn + sko, \
                            &smem[bufN + 8192 + tid*8]);
#define S_STG_ALO(ss) { const int idx_ = (ss)*8 + wid; \
    g2l16(Ql + ((size_t)((rowBlock >> 5) + (idx_ >> 1)) * 128 + (kbn >> 4) + (idx_ & 1)) * 512 + lane*8, \
          &smem[bufN + 12288 + idx_*512 + lane*8]); }
#define S_STG_BLO     { const int idx_ = wid; \
    g2l16(Kl + ((size_t)((colBlock >> 5) + (idx_ >> 1)) * 128 + (kbn >> 4) + (idx_ & 1)) * 512 + lane*8, \
          &smem[bufN + 20480 + idx_*512 + lane*8]); }

#define S_PHASE(qq) { \
    bf16x8 ah[2], bh[2], al[2], bl[2]; \
    const int cl_ = (qq)*2 + lh; \
    _Pragma("unroll") for (int r_ = 0; r_ < 2; ++r_) \
      ah[r_] = *(const bf16x8*)&smem[bufC + ((wm*64 + r_*32 + l31) << 5) + ((cl_ ^ rkey) << 3)]; \
    _Pragma("unroll") for (int c_ = 0; c_ < 2; ++c_) \
      bh[c_] = *(const bf16x8*)&smem[bufC + 8192 + ((wn*64 + c_*32 + l31) << 5) + ((cl_ ^ rkey) << 3)]; \
    _Pragma("unroll") for (int r_ = 0; r_ < 2; ++r_) \
      al[r_] = *(const bf16x8*)&smem[bufC + 12288 + ((wm*2 + r_)*2 + (qq))*512 + lane*8]; \
    _Pragma("unroll") for (int c_ = 0; c_ < 2; ++c_) \
      bl[c_] = *(const bf16x8*)&smem[bufC + 20480 + ((wn*2 + c_)*2 + (qq))*512 + lane*8]; \
    __builtin_amdgcn_s_setprio(1); \
    _Pragma("unroll") for (int r_ = 0; r_ < 2; ++r_) \
      _Pragma("unroll") for (int c_ = 0; c_ < 2; ++c_) { \
        acc[r_][c_] = MFMA32(ah[r_], bh[c_], acc[r_][c_]); \
        acc[r_][c_] = MFMA32(ah[r_], bl[c_], acc[r_][c_]); \
        acc[r_][c_] = MFMA32(al[r_], bh[c_], acc[r_][c_]); } \
    __builtin_amdgcn_s_setprio(0); }

  {
    const size_t kbn = 0; const int bufN = 0;
    S_STG_AHI(0) S_STG_AHI(1) S_STG_BHI
    S_STG_ALO(0) S_STG_ALO(1) S_STG_BLO
  }
  asm volatile("s_waitcnt vmcnt(0)" ::: "memory");
  __builtin_amdgcn_s_barrier();

  for (int t = 0; t < 64; ++t) {
    const int bufC = (t & 1) * 24576;
    const int bufN = bufC ^ 24576;
    const size_t kbn = (size_t)(t + 1) * 32;
    if (t < 63) { S_STG_AHI(0) S_STG_AHI(1) S_STG_BHI }
    __builtin_amdgcn_sched_barrier(0);
    S_PHASE(0)
    if (t < 63) { S_STG_ALO(0) S_STG_ALO(1) S_STG_BLO }
    __builtin_amdgcn_sched_barrier(0);
    S_PHASE(1)
    asm volatile("s_waitcnt vmcnt(0)" ::: "memory");
    __builtin_amdgcn_s_barrier();
  }
#undef S_PHASE
#undef S_STG_BLO
#undef S_STG_ALO
#undef S_STG_BHI
#undef S_STG_AHI

  // packed-S epilogue: only causal 128-blocks (col>>7 <= row>>7) are stored.
  const int r0 = rowBlock + wm * 64, c0 = colBlock + wn * 64;
#pragma unroll
  for (int r = 0; r < 2; ++r)
#pragma unroll
    for (int c = 0; c < 2; ++c) {
      const int col = c0 + c * 32 + l31;
#pragma unroll
      for (int g = 0; g < 4; ++g)
#pragma unroll
        for (int e = 0; e < 4; ++e) {
          const int row = r0 + r * 32 + 8 * g + 4 * lh + e;
          if ((col >> 7) <= (row >> 7))
            S[s_base(row) + col] = acc[r][c][g * 4 + e];
        }
    }
}

__device__ __forceinline__ void projv_body(
    const u16* __restrict__ Xh, const u16* __restrict__ Wvh,
    u16* __restrict__ Vt, int vbid, u16* smem)
{
  const int rowBlock = (vbid >> 4) * 256;
  const int colBlock = (vbid & 15) * 128;
  const int tid  = threadIdx.x;
  const int wid  = tid >> 6, lane = tid & 63;
  const int wm   = wid >> 1, wn = wid & 1;      // wave tile: 64 rows x 64 cols
  const int l31  = lane & 31, lh = lane >> 5;
  const int srow = tid >> 2, schunk = tid & 3;
  const int sko  = ((schunk ^ ((srow >> 1) & 3)) << 3);
  const int rkey = (l31 >> 1) & 3;

  f32x16 acc[2][2];
  {
    const f32x16 z16 = {0.f,0.f,0.f,0.f,0.f,0.f,0.f,0.f,0.f,0.f,0.f,0.f,0.f,0.f,0.f,0.f};
#pragma unroll
    for (int r = 0; r < 2; ++r)
#pragma unroll
      for (int c = 0; c < 2; ++c) acc[r][c] = z16;
  }

#define V_STGA(hh, pp) g2l16(Xh + (size_t)(rowBlock + (pp)*128 + srow) * DM + kbn + (hh)*32 + sko, \
                             &smem[bufN + (hh)*8192 + (pp)*4096 + tid*8]);
#define V_STGB(hh)     g2l16(Wvh + (size_t)(colBlock + srow) * DM + kbn + (hh)*32 + sko, \
                             &smem[bufN + 16384 + (hh)*4096 + tid*8]);

#define V_PH(qq, STMT) { \
    __builtin_amdgcn_sched_barrier(0); \
    STMT; \
    bf16x8 ah[2], bh[2]; \
    const int cl_ = ((qq) & 1) * 2 + lh; \
    const int hx_ = (qq) >> 1; \
    _Pragma("unroll") for (int r_ = 0; r_ < 2; ++r_) \
      ah[r_] = *(const bf16x8*)&smem[bufC + ((hx_*256 + wm*64 + r_*32 + l31) << 5) + ((cl_ ^ rkey) << 3)]; \
    _Pragma("unroll") for (int c_ = 0; c_ < 2; ++c_) \
      bh[c_] = *(const bf16x8*)&smem[bufC + 16384 + ((hx_*128 + wn*64 + c_*32 + l31) << 5) + ((cl_ ^ rkey) << 3)]; \
    __builtin_amdgcn_s_setprio(1); \
    _Pragma("unroll") for (int r_ = 0; r_ < 2; ++r_) \
      _Pragma("unroll") for (int c_ = 0; c_ < 2; ++c_) \
        acc[r_][c_] = MFMA32(ah[r_], bh[c_], acc[r_][c_]); \
    __builtin_amdgcn_s_setprio(0); }

  {
    const size_t kbn = 0; const int bufN = 0;
    V_STGA(0,0) V_STGA(0,1) V_STGA(1,0) V_STGA(1,1) V_STGB(0) V_STGB(1)
  }
  asm volatile("s_waitcnt vmcnt(0)" ::: "memory");
  __builtin_amdgcn_s_barrier();

  for (int t = 0; t < 32; ++t) {
    const int bufC = (t & 1) * 24576;
    const int bufN = bufC ^ 24576;
    const size_t kbn = (size_t)(t + 1) * 64;
    const bool more = (t < 31);
    V_PH(0, if (more) { V_STGA(0,0) V_STGA(0,1) V_STGB(0) })
    V_PH(1, if (more) { V_STGA(1,0) V_STGA(1,1) V_STGB(1) })
    V_PH(2, ;)
    V_PH(3, ;)
    asm volatile("s_waitcnt vmcnt(0)" ::: "memory");
    __builtin_amdgcn_s_barrier();
  }
#undef V_PH
#undef V_STGB
#undef V_STGA

  // epilogue: transposed store Vt[col][row], 4 consecutive rows packed
  const int vr0 = rowBlock + wm * 64;
#pragma unroll
  for (int r = 0; r < 2; ++r)
#pragma unroll
    for (int c = 0; c < 2; ++c) {
      const int col = colBlock + wn * 64 + c * 32 + l31;
#pragma unroll
      for (int g = 0; g < 4; ++g) {
        ushort4 pk;
        pk.x = f2bf(acc[r][c][g * 4 + 0]);
        pk.y = f2bf(acc[r][c][g * 4 + 1]);
        pk.z = f2bf(acc[r][c][g * 4 + 2]);
        pk.w = f2bf(acc[r][c][g * 4 + 3]);
        *(ushort4*)(Vt + (size_t)col * SEQ + vr0 + r * 32 + 8 * g + 4 * lh) = pk;
      }
    }
}

__global__ __launch_bounds__(512, 2) void k_scores_v(
    const u16* __restrict__ Qh, const u16* __restrict__ Ql,
    const u16* __restrict__ Kh, const u16* __restrict__ Kl,
    float* __restrict__ S,
    const u16* __restrict__ Xh, const u16* __restrict__ Wvh,
    u16* __restrict__ Vt)
{
  __shared__ __align__(16) u16 smem[49152];     // 96 KiB, shared by both paths
  if (blockIdx.x < 272) {
    scores_body(Qh, Ql, Kh, Kl, S, smem);
  } else {
    projv_body(Xh, Wvh, Vt, blockIdx.x - 272, smem);
  }
}

// Row softmax (causal) + inverted dropout; packed S fp32 -> P bf16 (zero-padded).
__global__ __launch_bounds__(256) void k_softmax_dropout(const float* __restrict__ S,
                                                         u16* __restrict__ P) {
  const int row = blockIdx.x;
  const int n = row + 1;
  const int nt = (n + 1023) >> 10;
  const int tid = threadIdx.x;
  __shared__ float buf[SEQ];
  __shared__ float red[4];
  __shared__ float bcast;
  const float* srow = S + s_base(row);

  float lmax = -INFINITY;
  for (int t = 0; t < nt; ++t) {
    int j4 = tid + t * 256;
    float4 v = *(const float4*)(srow + (size_t)j4 * 4);
    int b = j4 * 4;
    float x0 = (b + 0 < n) ? v.x : -INFINITY;
    float x1 = (b + 1 < n) ? v.y : -INFINITY;
    float x2 = (b + 2 < n) ? v.z : -INFINITY;
    float x3 = (b + 3 < n) ? v.w : -INFINITY;
    buf[b + 0] = x0; buf[b + 1] = x1; buf[b + 2] = x2; buf[b + 3] = x3;
    lmax = fmaxf(lmax, fmaxf(fmaxf(x0, x1), fmaxf(x2, x3)));
  }
  for (int off = 32; off > 0; off >>= 1) lmax = fmaxf(lmax, __shfl_down(lmax, off, 64));
  if ((tid & 63) == 0) red[tid >> 6] = lmax;
  __syncthreads();
  if (tid == 0) bcast = fmaxf(fmaxf(red[0], red[1]), fmaxf(red[2], red[3]));
  __syncthreads();
  const float m = bcast;

  float lsum = 0.f;
  for (int t = 0; t < nt; ++t) {
    int b = (tid + t * 256) * 4;
    float e0 = expf(buf[b + 0] - m);
    float e1 = expf(buf[b + 1] - m);
    float e2 = expf(buf[b + 2] - m);
    float e3 = expf(buf[b + 3] - m);
    buf[b + 0] = e0; buf[b + 1] = e1; buf[b + 2] = e2; buf[b + 3] = e3;
    lsum += (e0 + e1) + (e2 + e3);
  }
  for (int off = 32; off > 0; off >>= 1) lsum += __shfl_down(lsum, off, 64);
  if ((tid & 63) == 0) red[tid >> 6] = lsum;
  __syncthreads();
  if (tid == 0) bcast = (red[0] + red[1]) + (red[2] + red[3]);
  __syncthreads();
  const float total = bcast;

  u16* prow = P + (size_t)row * SEQ;
  const int zeroEnd = ((row >> 7) + 1) << 7;
  for (int j = tid; j < zeroEnd; j += 256) {
    float out = 0.f;
    if (j < n) {
      const float w = buf[j] / total;
      out = dropout_keep((u32)(row * SEQ + j)) ? w * 2.0f : 0.f;
    }
    prow[j] = f2bf(out);
  }
}

// context = P @ V (plain bf16, causal-truncated K-loop), fp32 out; heavy rows first.
__global__ __launch_bounds__(256) void k_pv(const u16* __restrict__ P,
                                            const u16* __restrict__ Vt,
                                            float* __restrict__ O) {
  __shared__ __align__(16) u16 smem[16384];
  const int by = (SEQ / 128 - 1) - blockIdx.y;
  f32x4 acc[4][4];
  gemm_core(P, Vt, SEQ, SEQ, by * 128, blockIdx.x * 128, (by + 1) * 128, acc, smem);

  const int lane = threadIdx.x & 63, wid = threadIdx.x >> 6;
  const int r0 = by * 128 + ((wid & 1) << 6) + ((lane >> 4) << 2);
  const int c0 = blockIdx.x * 128 + ((wid >> 1) << 6) + (lane & 15);
#pragma unroll
  for (int r = 0; r < 4; ++r)
#pragma unroll
    for (int c = 0; c < 4; ++c)
#pragma unroll
      for (int e = 0; e < 4; ++e)
        O[(size_t)(r0 + r * 16 + e) * DM + (c0 + c * 16)] = acc[r][c][e];
}

extern "C" void kernel_launch(void* const* d_in, const int* in_sizes, int n_in,
                              void* d_out, int out_size, void* d_ws, size_t ws_size,
                              hipStream_t stream) {
  const float* x  = (const float*)d_in[0];
  const float* Wq = (const float*)d_in[1];
  const float* Wk = (const float*)d_in[2];
  const float* Wv = (const float*)d_in[3];

  // workspace layout (u16 elements; <=152 MiB).
  const size_t PL = (size_t)SEQ * DM;   // 16 MiB/plane
  const size_t WL = (size_t)DM * DM;    // 8 MiB/plane
  u16* base = (u16*)d_ws;
  u16* Qh = base;                // [SEQ][DM] row-major
  u16* Ql = Qh + PL;             // FT32
  u16* Kh = Ql + PL;             // row-major
  u16* Kl = Kh + PL;             // FT32
  u16* Vt = Kl + PL;             // [DM][SEQ]
  u16* P  = base;                // [SEQ][SEQ] bf16, overlays Qh+Ql (dead by then)
  u16* regA = Vt + PL;           // offset 80 MiB
  u16* Xh  = regA;               // [SEQ][DM] row-major  (LIVE through k_scores_v)
  u16* Xl  = Xh + PL;            // FT32 (dead after proj_qk)
  u16* Wqh = Xl + PL;            // (dead after proj_qk)
  u16* Wql = Wqh + WL;
  u16* Wkh = Wql + WL;
  u16* Wkl = Wkh + WL;
  u16* Wvh = Wkl + WL;           // LIVE through k_scores_v
  float* S = (float*)Xl;         // PACKED causal S, 34.6 MiB: overlays Xl..Wkh
                                 // (all dead when k_scores_v runs); does NOT
                                 // touch Xh or Wvh (projv inputs).

  const float rscale = 1.0f / sqrtf(2048.0f);
  k_split_all<<<dim3(4096 + 3 * 1024), dim3(256), 0, stream>>>(
      x, Xh, Xl, Wq, Wk, Wv, Wqh, Wql, Wkh, Wkl, Wvh);
  k_proj_qk<<<dim3(DM / 256, SEQ / 256, 2), dim3(512), 0, stream>>>(
      Xh, Xl, Wqh, Wql, Wkh, Wkl, Qh, Ql, Kh, Kl, rscale);
  k_scores_v<<<dim3(272 + 256), dim3(512), 0, stream>>>(
      Qh, Ql, Kh, Kl, S, Xh, Wvh, Vt);
  k_softmax_dropout<<<dim3(SEQ), dim3(256), 0, stream>>>(S, P);
  k_pv<<<dim3(DM / 128, SEQ / 128), dim3(256), 0, stream>>>(P, Vt, (float*)d_out);
}